// Round 1
// baseline (941.467 us; speedup 1.0000x reference)
//
#include <hip/hip_runtime.h>
#include <math.h>

// CCALayer3D: x[4,64,32,128,128] fp32
//   y[b,c]  = std(x[b,c]) + mean(x[b,c])        (biased std over spatial)
//   h       = relu(w1 @ y + b1)                 w1:[4,64]
//   g       = sigmoid(w2 @ h + b2)              w2:[64,4]
//   out     = x * g[b,c]
// Memory-bound: 512MiB read (stats) + 512MiB read + 512MiB write (scale)
// ~1.61 GB => ~256 us floor at 6.3 TB/s.

#define CCH 64
#define BATCH 4
#define NCH (BATCH * CCH)            // 256 channels
#define SPATIAL (32 * 128 * 128)     // 524288 elements per channel
#define NVEC (SPATIAL / 4)           // 131072 float4 per channel

#define BPC1 16                      // blocks per channel, stats kernel
#define BPC3 64                      // blocks per channel, scale kernel

// ---------------- Kernel 1: per-channel sum & sumsq ----------------
// grid = NCH*BPC1 blocks x 256 threads. Each thread: 32 float4 loads.
__global__ __launch_bounds__(256) void cca_stats(const float* __restrict__ x,
                                                 double* __restrict__ sums) {
    const int bc  = blockIdx.x / BPC1;
    const int blk = blockIdx.x % BPC1;
    const float4* xc = (const float4*)(x + (size_t)bc * SPATIAL);
    const int per_block = NVEC / BPC1;           // 8192 float4
    const int base = blk * per_block;

    float s1 = 0.f, s2 = 0.f;
    for (int i = threadIdx.x; i < per_block; i += 256) {
        float4 v = xc[base + i];
        s1 += (v.x + v.y) + (v.z + v.w);
        s2 += (v.x * v.x + v.y * v.y) + (v.z * v.z + v.w * v.w);
    }

    // wave (64-lane) butterfly reduce in double
    double d1 = (double)s1, d2 = (double)s2;
    #pragma unroll
    for (int off = 32; off > 0; off >>= 1) {
        d1 += __shfl_down(d1, off, 64);
        d2 += __shfl_down(d2, off, 64);
    }
    __shared__ double sh1[4], sh2[4];
    const int wave = threadIdx.x >> 6;
    const int lane = threadIdx.x & 63;
    if (lane == 0) { sh1[wave] = d1; sh2[wave] = d2; }
    __syncthreads();
    if (threadIdx.x == 0) {
        double t1 = (sh1[0] + sh1[1]) + (sh1[2] + sh1[3]);
        double t2 = (sh2[0] + sh2[1]) + (sh2[2] + sh2[3]);
        atomicAdd(&sums[bc * 2 + 0], t1);
        atomicAdd(&sums[bc * 2 + 1], t2);
    }
}

// ---------------- Kernel 2: stats -> MLP -> gate g[256] ----------------
__global__ __launch_bounds__(256) void cca_mlp(const double* __restrict__ sums,
                                               const float* __restrict__ w1,
                                               const float* __restrict__ b1,
                                               const float* __restrict__ w2,
                                               const float* __restrict__ b2,
                                               float* __restrict__ g) {
    __shared__ float y[NCH];          // [b][c]
    __shared__ float h[BATCH][4];
    const int t = threadIdx.x;

    if (t < NCH) {
        double s1 = sums[t * 2 + 0];
        double s2 = sums[t * 2 + 1];
        double mean = s1 / (double)SPATIAL;
        double var  = s2 / (double)SPATIAL - mean * mean;
        if (var < 0.0) var = 0.0;
        y[t] = (float)(sqrt(var) + mean);
    }
    __syncthreads();

    if (t < BATCH * 4) {              // 16 threads: h[b][r]
        const int b = t >> 2, r = t & 3;
        float acc = b1[r];
        #pragma unroll
        for (int c = 0; c < CCH; ++c) acc += w1[r * CCH + c] * y[b * CCH + c];
        h[b][r] = acc > 0.f ? acc : 0.f;
    }
    __syncthreads();

    if (t < NCH) {                    // g[b][c] = sigmoid(w2[c,:] . h[b,:] + b2[c])
        const int b = t / CCH, c = t % CCH;
        float acc = b2[c];
        #pragma unroll
        for (int r = 0; r < 4; ++r) acc += w2[c * 4 + r] * h[b][r];
        g[t] = 1.f / (1.f + __expf(-acc));
    }
}

// ---------------- Kernel 3: out = x * g[bc] ----------------
// grid = NCH*BPC3 blocks x 256 threads. g is wave-uniform per block.
__global__ __launch_bounds__(256) void cca_scale(const float* __restrict__ x,
                                                 const float* __restrict__ g,
                                                 float* __restrict__ out) {
    const int bc  = blockIdx.x / BPC3;
    const int blk = blockIdx.x % BPC3;
    const float gv = g[bc];
    const int per_block = NVEC / BPC3;            // 2048 float4
    const size_t base = (size_t)bc * NVEC + (size_t)blk * per_block;
    const float4* xv = (const float4*)x;
    float4* ov = (float4*)out;
    #pragma unroll 4
    for (int i = threadIdx.x; i < per_block; i += 256) {
        float4 v = xv[base + i];
        v.x *= gv; v.y *= gv; v.z *= gv; v.w *= gv;
        ov[base + i] = v;
    }
}

extern "C" void kernel_launch(void* const* d_in, const int* in_sizes, int n_in,
                              void* d_out, int out_size, void* d_ws, size_t ws_size,
                              hipStream_t stream) {
    const float* x  = (const float*)d_in[0];
    const float* w1 = (const float*)d_in[1];
    const float* b1 = (const float*)d_in[2];
    const float* w2 = (const float*)d_in[3];
    const float* b2 = (const float*)d_in[4];
    float* out = (float*)d_out;

    // ws layout: [0, 4096): double sums[256][2]; [4096, 5120): float g[256]
    double* sums = (double*)d_ws;
    float* g = (float*)((char*)d_ws + NCH * 2 * sizeof(double));

    hipMemsetAsync(d_ws, 0, NCH * 2 * sizeof(double), stream);

    cca_stats<<<NCH * BPC1, 256, 0, stream>>>(x, sums);
    cca_mlp<<<1, 256, 0, stream>>>(sums, w1, b1, w2, b2, g);
    cca_scale<<<NCH * BPC3, 256, 0, stream>>>(x, g, out);
}